// Round 1
// baseline (59.043 us; speedup 1.0000x reference)
//
#include <hip/hip_runtime.h>

// EquivariantProductBasisBlock (MACE symmetric contraction, nu=3) on gfx950.
//
// Rewrite: Horner recursion == polynomial  y = sum_t sum_p w_t[p,c] * T_t[m,p],
//   T3[m,p] = sum_{ijk} U3[ijk,m,p] x_i x_j x_k  (only symmetric part survives)
// -> symmetrize U on device into 165/45/9-monomial tables (9.5 KB), stage in
//    LDS, one thread per (node, channel), fused Wlin epilogue per 2-node block.

#define K9 9
#define NC 128
#define NE 10
#define NCOL3 12                      // L0: p=0..2 | L1: 3 + m*3 + p
#define NCOL2 8                       // L0: p=0..1 | L1: 2 + m*2 + p
#define NCOL1 4                       // L0: 0      | L1: 1 + m
#define NS3 165
#define NS2 45
#define OFF_C2 (NS3*NCOL3)            // 1980 floats
#define OFF_C1 (OFF_C2 + NS2*NCOL2)   // 2340 floats
#define TBL_FLOATS (OFF_C1 + K9*NCOL1) // 2376 floats = 9504 B

__global__ void build_tables_kernel(
    const float* __restrict__ U1_0, const float* __restrict__ U2_0, const float* __restrict__ U3_0,
    const float* __restrict__ U1_1, const float* __restrict__ U2_1, const float* __restrict__ U3_1,
    float* __restrict__ tbl)
{
  int t = threadIdx.x;
  if (t < NS3) {
    // decode multiset index t -> (I <= J <= Kk)
    int I = 0, J = 0, Kk = 0, s = 0;
    for (int i = 0; i < K9; ++i)
      for (int j = i; j < K9; ++j)
        for (int k = j; k < K9; ++k) {
          if (s == t) { I = i; J = j; Kk = k; }
          ++s;
        }
    float col[NCOL3];
    for (int q = 0; q < NCOL3; ++q) col[q] = 0.f;
    int pm[6][3] = {{I,J,Kk},{I,Kk,J},{J,I,Kk},{J,Kk,I},{Kk,I,J},{Kk,J,I}};
    for (int p = 0; p < 6; ++p) {
      bool dup = false;
      for (int q = 0; q < p; ++q)
        if (pm[q][0]==pm[p][0] && pm[q][1]==pm[p][1] && pm[q][2]==pm[p][2]) dup = true;
      if (dup) continue;
      int base = (pm[p][0]*K9 + pm[p][1])*K9 + pm[p][2];
      // U3_0: (9,9,9,1,3) ; U3_1: (9,9,9,3,3)
      for (int p3 = 0; p3 < 3; ++p3) col[p3] += U3_0[base*3 + p3];
      for (int m = 0; m < 3; ++m)
        for (int p3 = 0; p3 < 3; ++p3) col[3 + m*3 + p3] += U3_1[base*9 + m*3 + p3];
    }
    for (int q = 0; q < NCOL3; ++q) tbl[t*NCOL3 + q] = col[q];
  } else if (t < NS3 + NS2) {
    int s2 = t - NS3;
    int I = 0, J = 0, s = 0;
    for (int i = 0; i < K9; ++i)
      for (int j = i; j < K9; ++j) { if (s == s2) { I = i; J = j; } ++s; }
    float col[NCOL2];
    for (int q = 0; q < NCOL2; ++q) col[q] = 0.f;
    int pm2[2][2] = {{I,J},{J,I}};
    int np = (I == J) ? 1 : 2;
    for (int p = 0; p < np; ++p) {
      int base = pm2[p][0]*K9 + pm2[p][1];
      // U2_0: (9,9,1,2) ; U2_1: (9,9,3,2)
      for (int p2 = 0; p2 < 2; ++p2) col[p2] += U2_0[base*2 + p2];
      for (int m = 0; m < 3; ++m)
        for (int p2 = 0; p2 < 2; ++p2) col[2 + m*2 + p2] += U2_1[(base*3 + m)*2 + p2];
    }
    for (int q = 0; q < NCOL2; ++q) tbl[OFF_C2 + s2*NCOL2 + q] = col[q];
  } else if (t < NS3 + NS2 + K9) {
    int i = t - NS3 - NS2;
    // U1_0: (9,1,1) ; U1_1: (9,3,1)
    tbl[OFF_C1 + i*NCOL1 + 0] = U1_0[i];
    for (int m = 0; m < 3; ++m) tbl[OFF_C1 + i*NCOL1 + 1 + m] = U1_1[i*3 + m];
  }
}

__global__ __launch_bounds__(256) void epbb_main_kernel(
    const float* __restrict__ xg,    // [N,128,9]
    const float* __restrict__ na,    // [N,10] one-hot
    const float* __restrict__ sc,    // [N,512]
    const float* __restrict__ W1_0, const float* __restrict__ W2_0, const float* __restrict__ W3_0,
    const float* __restrict__ Wlin0,
    const float* __restrict__ W1_1, const float* __restrict__ W2_1, const float* __restrict__ W3_1,
    const float* __restrict__ Wlin1,
    const float* __restrict__ tbl,
    float* __restrict__ out)         // [N,512]
{
  __shared__ __align__(16) float lc[TBL_FLOATS];
  __shared__ __align__(16) float ly[2*NC*4];
  for (int q = threadIdx.x; q < TBL_FLOATS; q += 256) lc[q] = tbl[q];

  const int t  = threadIdx.x;
  const int nl = t >> 7;           // node within block (0..1)
  const int c  = t & 127;          // channel
  const int n  = blockIdx.x*2 + nl;

  // node features for this (n,c)
  const float* xp = xg + ((long)n*NC + c)*K9;
  float xr[K9];
  #pragma unroll
  for (int k = 0; k < K9; ++k) xr[k] = xp[k];

  // species (exact one-hot)
  int e = 0;
  const float* nap = na + n*NE;
  #pragma unroll
  for (int q = 0; q < NE; ++q) e = (nap[q] > 0.5f) ? q : e;

  // per-(element, channel) path weights  W_t: (E, P_t, C)
  const float w10  = W1_0[e*NC + c];
  const float w20a = W2_0[(e*2+0)*NC + c], w20b = W2_0[(e*2+1)*NC + c];
  const float w30a = W3_0[(e*3+0)*NC + c], w30b = W3_0[(e*3+1)*NC + c], w30c = W3_0[(e*3+2)*NC + c];
  const float w11  = W1_1[e*NC + c];
  const float w21a = W2_1[(e*2+0)*NC + c], w21b = W2_1[(e*2+1)*NC + c];
  const float w31a = W3_1[(e*3+0)*NC + c], w31b = W3_1[(e*3+1)*NC + c], w31c = W3_1[(e*3+2)*NC + c];

  __syncthreads();   // coefficient tables staged

  const float4* C3v = (const float4*)lc;              // NS3 rows x 3 float4
  const float4* C2v = (const float4*)(lc + OFF_C2);   // NS2 rows x 2 float4
  const float4* C1v = (const float4*)(lc + OFF_C1);   // K9  rows x 1 float4

  float a3[NCOL3], a2[NCOL2], a1[NCOL1];
  #pragma unroll
  for (int q = 0; q < NCOL3; ++q) a3[q] = 0.f;
  #pragma unroll
  for (int q = 0; q < NCOL2; ++q) a2[q] = 0.f;
  #pragma unroll
  for (int q = 0; q < NCOL1; ++q) a1[q] = 0.f;

  int s3 = 0, s2 = 0;
  #pragma unroll
  for (int i = 0; i < K9; ++i) {
    const float xi = xr[i];
    float4 c1 = C1v[i];
    a1[0] += c1.x*xi; a1[1] += c1.y*xi; a1[2] += c1.z*xi; a1[3] += c1.w*xi;
    #pragma unroll
    for (int j = i; j < K9; ++j) {
      const float pij = xi * xr[j];
      float4 b0 = C2v[s2*2+0], b1 = C2v[s2*2+1];
      a2[0] += b0.x*pij; a2[1] += b0.y*pij; a2[2] += b0.z*pij; a2[3] += b0.w*pij;
      a2[4] += b1.x*pij; a2[5] += b1.y*pij; a2[6] += b1.z*pij; a2[7] += b1.w*pij;
      ++s2;
      #pragma unroll
      for (int k = j; k < K9; ++k) {
        const float pijk = pij * xr[k];
        float4 u0 = C3v[s3*3+0], u1 = C3v[s3*3+1], u2 = C3v[s3*3+2];
        a3[0] += u0.x*pijk; a3[1]  += u0.y*pijk; a3[2]  += u0.z*pijk; a3[3]  += u0.w*pijk;
        a3[4] += u1.x*pijk; a3[5]  += u1.y*pijk; a3[6]  += u1.z*pijk; a3[7]  += u1.w*pijk;
        a3[8] += u2.x*pijk; a3[9]  += u2.y*pijk; a3[10] += u2.z*pijk; a3[11] += u2.w*pijk;
        ++s3;
      }
    }
  }

  // y[c,m]: combine path sums with per-element weights
  const float y0   = w10*a1[0] + w20a*a2[0] + w20b*a2[1] + w30a*a3[0]  + w30b*a3[1]  + w30c*a3[2];
  const float y1m0 = w11*a1[1] + w21a*a2[2] + w21b*a2[3] + w31a*a3[3]  + w31b*a3[4]  + w31c*a3[5];
  const float y1m1 = w11*a1[2] + w21a*a2[4] + w21b*a2[5] + w31a*a3[6]  + w31b*a3[7]  + w31c*a3[8];
  const float y1m2 = w11*a1[3] + w21a*a2[6] + w21b*a2[7] + w31a*a3[9]  + w31b*a3[10] + w31c*a3[11];

  ((float4*)ly)[nl*NC + c] = make_float4(y0, y1m0, y1m1, y1m2);
  __syncthreads();

  // fused linear epilogue: thread -> (nl, d=c); z[n,d,m] = inv * sum_c y[n,c,m] Wlin[c,d]
  const int d = c;
  float z0 = 0.f, za = 0.f, zb = 0.f, zc = 0.f;
  const float4* yrow = ((const float4*)ly) + nl*NC;
  for (int cc = 0; cc < NC; ++cc) {
    float4 yv = yrow[cc];                 // LDS broadcast (wave-uniform addr)
    float wl0 = Wlin0[cc*NC + d];         // coalesced across lanes
    float wl1 = Wlin1[cc*NC + d];
    z0 += yv.x*wl0; za += yv.y*wl1; zb += yv.z*wl1; zc += yv.w*wl1;
  }
  const float inv = 0.088388347648318447f;   // 1/sqrt(128)
  const long orow = (long)n*512;
  out[orow + d]           = z0*inv + sc[orow + d];
  out[orow + 128 + 3*d+0] = za*inv + sc[orow + 128 + 3*d+0];
  out[orow + 128 + 3*d+1] = zb*inv + sc[orow + 128 + 3*d+1];
  out[orow + 128 + 3*d+2] = zc*inv + sc[orow + 128 + 3*d+2];
}

extern "C" void kernel_launch(void* const* d_in, const int* in_sizes, int n_in,
                              void* d_out, int out_size, void* d_ws, size_t ws_size,
                              hipStream_t stream) {
  // setup_inputs() dict order:
  const float* xg   = (const float*)d_in[0];   // node_feats [N,128,9]
  const float* na   = (const float*)d_in[1];   // node_attrs [N,10]
  const float* sc   = (const float*)d_in[2];   // sc [N,512]
  const float* U1_0 = (const float*)d_in[3];
  const float* W1_0 = (const float*)d_in[4];
  const float* U2_0 = (const float*)d_in[5];
  const float* W2_0 = (const float*)d_in[6];
  const float* U3_0 = (const float*)d_in[7];
  const float* W3_0 = (const float*)d_in[8];
  const float* Wl0  = (const float*)d_in[9];
  const float* U1_1 = (const float*)d_in[10];
  const float* W1_1 = (const float*)d_in[11];
  const float* U2_1 = (const float*)d_in[12];
  const float* W2_1 = (const float*)d_in[13];
  const float* U3_1 = (const float*)d_in[14];
  const float* W3_1 = (const float*)d_in[15];
  const float* Wl1  = (const float*)d_in[16];

  float* tbl = (float*)d_ws;                   // 9504 B of workspace
  const int N = in_sizes[0] / (NC * K9);

  hipLaunchKernelGGL(build_tables_kernel, dim3(1), dim3(256), 0, stream,
                     U1_0, U2_0, U3_0, U1_1, U2_1, U3_1, tbl);
  hipLaunchKernelGGL(epbb_main_kernel, dim3(N/2), dim3(256), 0, stream,
                     xg, na, sc, W1_0, W2_0, W3_0, Wl0, W1_1, W2_1, W3_1, Wl1, tbl,
                     (float*)d_out);
}